// Round 13
// baseline (321.875 us; speedup 1.0000x reference)
//
#include <hip/hip_runtime.h>
#include <hip/hip_cooperative_groups.h>

namespace cg = cooperative_groups;

#define D 32
#define GBITS 6
#define GSIZE 64               // rows per group
#define BLKP 256               // pre_hist block size
#define PPC 2048               // pairs per hist/scatter chunk
#define IPT_H 8                // PPC / BLKP
#define CBLK 512               // coop block size
#define IPT_S 4                // PPC / CBLK
#define GRID 512               // coop grid (2 blocks/CU guaranteed co-resident)
#define CAP 2560               // LDS item capacity per group

typedef unsigned long long ull;

static __device__ __forceinline__ unsigned short f2h(float f) {
    _Float16 h = (_Float16)f;
    return __builtin_bit_cast(unsigned short, h);
}
static __device__ __forceinline__ float h2f(unsigned short u) {
    return (float)__builtin_bit_cast(_Float16, u);
}
static __device__ __forceinline__ float ftanh(float u) {
    u = fminf(fmaxf(u, -15.f), 15.f);
    float e = __expf(2.f * u);
    return (e - 1.f) / (e + 1.f);
}

// ---------------------------------------------------------------------------
// K1 (fused): blocks [0,nbN) per-node precompute (ab + f16 y_h);
//             blocks [nbN,...) blocked bin histogram (bin = row >> GBITS).
// ---------------------------------------------------------------------------
__global__ void k_pre_hist(const float* __restrict__ x,
                           const float* __restrict__ sheafW,
                           const float* __restrict__ linW,
                           const float* __restrict__ linb,
                           const int* __restrict__ ei,
                           float2* __restrict__ ab,
                           unsigned short* __restrict__ y_h,
                           int* __restrict__ bhist,
                           int N, int E2, int E, int nbN, int nblkH, int NBG) {
    if (blockIdx.x < nbN) {
        __shared__ float sW[D * D];
        __shared__ float sB[D];
        __shared__ float sS[2 * D];
        for (int i = threadIdx.x; i < D * D; i += blockDim.x) sW[i] = linW[i];
        if (threadIdx.x < D) sB[threadIdx.x] = linb[threadIdx.x];
        if (threadIdx.x < 2 * D) sS[threadIdx.x] = sheafW[threadIdx.x];
        __syncthreads();

        int n = blockIdx.x * blockDim.x + threadIdx.x;
        if (n >= N) return;

        float xv[D];
        const float4* xp = reinterpret_cast<const float4*>(x + (size_t)n * D);
#pragma unroll
        for (int i = 0; i < D / 4; ++i) {
            float4 v = xp[i];
            xv[4 * i + 0] = v.x; xv[4 * i + 1] = v.y;
            xv[4 * i + 2] = v.z; xv[4 * i + 3] = v.w;
        }

        float av = 0.f, bv = 0.f;
#pragma unroll
        for (int d = 0; d < D; ++d) { av += xv[d] * sS[d]; bv += xv[d] * sS[D + d]; }
        ab[n] = make_float2(av, bv);

        unsigned short yh[D];
#pragma unroll
        for (int j = 0; j < D; ++j) {
            float s = sB[j];
#pragma unroll
            for (int d = 0; d < D; ++d) s += xv[d] * sW[j * D + d];
            yh[j] = f2h(s);
        }
        uint4* dst = reinterpret_cast<uint4*>(y_h + (size_t)n * D);
        const uint4* src = reinterpret_cast<const uint4*>(yh);
#pragma unroll
        for (int q = 0; q < D / 8; ++q) dst[q] = src[q];
    } else {
        __shared__ int hist[1024];
        int blk = blockIdx.x - nbN;
        for (int i = threadIdx.x; i < NBG; i += BLKP) hist[i] = 0;
        __syncthreads();
        int base = blk * PPC;
#pragma unroll
        for (int k = 0; k < IPT_H; ++k) {
            int i = base + k * BLKP + threadIdx.x;
            if (i < E2) {
                int s = ei[i];
                int t = ei[E + i];
                atomicAdd(&hist[s >> GBITS], 1);
                atomicAdd(&hist[t >> GBITS], 1);
            }
        }
        __syncthreads();
        for (int i = threadIdx.x; i < NBG; i += BLKP)
            bhist[(size_t)i * nblkH + blk] = hist[i];
    }
}

// ---------------------------------------------------------------------------
// K2 (cooperative): scanA -> scanB -> scatter -> diag -> gather, separated by
// grid.sync().  Math identical to the round-12 separate kernels.
// ---------------------------------------------------------------------------
__global__ __launch_bounds__(CBLK, 4) void k_coop(
        const int* __restrict__ ei,
        const float2* __restrict__ ab,
        int* __restrict__ bhist,
        int* __restrict__ bsum,
        ull* __restrict__ binned,
        const unsigned short* __restrict__ y_h,
        const float* __restrict__ x,
        float* __restrict__ dsi,
        float* __restrict__ diag2,
        int* __restrict__ rbase_g,
        int* __restrict__ rcnt_g,
        float* __restrict__ out,
        int E2, int E, int nblkH, int NBG, int N, int MH, int nchA) {
    cg::grid_group grid = cg::this_grid();
    int bid = blockIdx.x, t = threadIdx.x;

    __shared__ int s512[CBLK];
    __shared__ int cursor[1024];
    __shared__ unsigned int sortedw[CAP];      // 10 KB
    __shared__ float rdiag[GSIZE];
    __shared__ int rhist[GSIZE];
    __shared__ int ss[GSIZE];
    __shared__ int rbase[GSIZE];
    __shared__ int rcnt[GSIZE];
    __shared__ int cur[GSIZE];
    __shared__ float sds[GSIZE];
    __shared__ float sdg[GSIZE];
    __shared__ int sgs[2];

    // ---- Phase A1: per-512-chunk exclusive scan of bhist, in place ----
    for (int c = bid; c < nchA; c += GRID) {
        int i = c * CBLK + t;
        int v = (i < MH) ? bhist[i] : 0;
        s512[t] = v;
        __syncthreads();
#pragma unroll
        for (int o = 1; o < CBLK; o <<= 1) {
            int tmp = (t >= o) ? s512[t - o] : 0;
            __syncthreads();
            s512[t] += tmp;
            __syncthreads();
        }
        if (i < MH) bhist[i] = s512[t] - v;
        if (t == CBLK - 1) bsum[c] = s512[t];
        __syncthreads();
    }
    grid.sync();

    // ---- Phase A2: block 0 exclusive-scans bsum[nchA] ----
    if (bid == 0) {
        int per = (nchA + CBLK - 1) / CBLK;
        int beg = t * per;
        int end_ = min(beg + per, nchA);
        int sum = 0;
        for (int i = beg; i < end_; ++i) sum += bsum[i];
        s512[t] = sum;
        __syncthreads();
#pragma unroll
        for (int o = 1; o < CBLK; o <<= 1) {
            int tmp = (t >= o) ? s512[t - o] : 0;
            __syncthreads();
            s512[t] += tmp;
            __syncthreads();
        }
        int run = s512[t] - sum;
        for (int i = beg; i < end_; ++i) { int v = bsum[i]; bsum[i] = run; run += v; }
    }
    grid.sync();

    // ---- Phase B: scatter (recompute maps, write bin-grouped binned) ----
    for (int c = bid; c < nblkH; c += GRID) {
        for (int i = t; i < NBG; i += CBLK) {
            int idx = i * nblkH + c;
            cursor[i] = bhist[idx] + bsum[idx >> 9];
        }
        __syncthreads();
        int base = c * PPC;
#pragma unroll
        for (int k = 0; k < IPT_S; ++k) {
            int i = base + k * CBLK + t;
            if (i < E2) {
                int s = ei[i];
                int tt = ei[E + i];
                float2 as = ab[s], at = ab[tt];
                float m  = ftanh(as.x + at.y);
                float mr = ftanh(at.x + as.y);
                ull hm = f2h(m), hmr = f2h(mr);
                int pos = atomicAdd(&cursor[s >> GBITS], 1);
                binned[pos] = ((ull)(unsigned)s << 48) | ((ull)(unsigned)tt << 32) | (hm << 16) | hmr;
                int pos2 = atomicAdd(&cursor[tt >> GBITS], 1);
                binned[pos2] = ((ull)(unsigned)tt << 48) | ((ull)(unsigned)s << 32) | (hmr << 16) | hm;
            }
        }
        __syncthreads();
    }
    grid.sync();

    // ---- Phase C: per-group diag + row histogram ----
    for (int g = bid; g < NBG; g += GRID) {
        if (t < GSIZE) { rdiag[t] = 0.f; rhist[t] = 0; }
        if (t < 2) {
            int gg = g + t;
            if (gg < NBG) {
                int idx = gg * nblkH;
                sgs[t] = bhist[idx] + bsum[idx >> 9];
            } else sgs[t] = E;
        }
        __syncthreads();
        int gstart = sgs[0], gend = sgs[1];
        for (int k = gstart + t; k < gend; k += CBLK) {
            ull it = binned[k];
            int r = (int)(it >> 48) & (GSIZE - 1);
            float m = h2f((unsigned short)((it >> 16) & 0xFFFF));
            atomicAdd(&rdiag[r], m * m);
            atomicAdd(&rhist[r], 1);
        }
        __syncthreads();
        int v = (t < GSIZE) ? rhist[t] : 0;
        if (t < GSIZE) ss[t] = v;
        __syncthreads();
#pragma unroll
        for (int o = 1; o < GSIZE; o <<= 1) {
            int tmp = 0;
            if (t < GSIZE && t >= o) tmp = ss[t - o];
            __syncthreads();
            if (t < GSIZE) ss[t] += tmp;
            __syncthreads();
        }
        int n0 = g << GBITS;
        if (t < GSIZE) {
            int n = n0 + t;
            if (n < N) {
                float dm = rdiag[t];
                float ds = rsqrtf(dm + 1.0f);
                dsi[n] = ds;
                diag2[n] = dm * ds * ds;
                rbase_g[n] = ss[t] - v;
                rcnt_g[n] = v;
            }
        }
        __syncthreads();
    }
    grid.sync();

    // ---- Phase D: per-group sort+gather+finalize ----
    for (int g = bid; g < NBG; g += GRID) {
        int n0 = g << GBITS;
        if (t < GSIZE) {
            int n = n0 + t;
            if (n < N) {
                sds[t] = dsi[n]; sdg[t] = diag2[n];
                int rb = rbase_g[n];
                rbase[t] = rb; cur[t] = rb; rcnt[t] = rcnt_g[n];
            } else { rbase[t] = 0; cur[t] = 0; rcnt[t] = 0; }
        }
        if (t == 0) {
            int idx = g * nblkH;
            sgs[0] = bhist[idx] + bsum[idx >> 9];
        }
        __syncthreads();
        int gstart = sgs[0];
        int cnt = 0;
        {
            int lastn = min(n0 + GSIZE, N) - 1;
            if (lastn >= n0) cnt = min(rbase[lastn - n0] + rcnt[lastn - n0], CAP);
        }

        for (int k = t; k < cnt; k += CBLK) {
            ull it = binned[gstart + k];
            int r = (int)(it >> 48) & (GSIZE - 1);
            unsigned int c = (unsigned int)((it >> 32) & 0xFFFF);
            float w = h2f((unsigned short)((it >> 16) & 0xFFFF)) *
                      h2f((unsigned short)(it & 0xFFFF)) * dsi[c];
            int pos = atomicAdd(&cur[r], 1);
            sortedw[pos] = (c << 16) | (unsigned int)f2h(w);
        }
        __syncthreads();

        int hw = t >> 5;
        int lane = t & 31;
        int rows = min(GSIZE, N - n0);
        for (int r = hw; r < rows; r += 16) {
            int beg = rbase[r];
            int end_ = beg + rcnt[r];
            float acc = 0.f;
            int k = beg;
            for (; k + 4 <= end_; k += 4) {
                unsigned int e0 = sortedw[k + 0];
                unsigned int e1 = sortedw[k + 1];
                unsigned int e2 = sortedw[k + 2];
                unsigned int e3 = sortedw[k + 3];
                float v0 = h2f(y_h[(size_t)(e0 >> 16) * D + lane]);
                float v1 = h2f(y_h[(size_t)(e1 >> 16) * D + lane]);
                float v2 = h2f(y_h[(size_t)(e2 >> 16) * D + lane]);
                float v3 = h2f(y_h[(size_t)(e3 >> 16) * D + lane]);
                acc += h2f((unsigned short)(e0 & 0xFFFF)) * v0;
                acc += h2f((unsigned short)(e1 & 0xFFFF)) * v1;
                acc += h2f((unsigned short)(e2 & 0xFFFF)) * v2;
                acc += h2f((unsigned short)(e3 & 0xFFFF)) * v3;
            }
            for (; k < end_; ++k) {
                unsigned int e = sortedw[k];
                acc += h2f((unsigned short)(e & 0xFFFF)) *
                       h2f(y_h[(size_t)(e >> 16) * D + lane]);
            }
            size_t p = (size_t)(n0 + r) * D + lane;
            float yown = h2f(y_h[p]);
            out[p] = x[p] - sdg[r] * yown + sds[r] * acc;
        }
        __syncthreads();
    }
}

extern "C" void kernel_launch(void* const* d_in, const int* in_sizes, int n_in,
                              void* d_out, int out_size, void* d_ws, size_t ws_size,
                              hipStream_t stream) {
    const float* x      = (const float*)d_in[0];
    const float* sheafW = (const float*)d_in[1];
    const float* linW   = (const float*)d_in[2];
    const float* linb   = (const float*)d_in[3];
    const int*   ei     = (const int*)d_in[4];

    int N  = in_sizes[0] / D;
    int E  = in_sizes[4] / 2;
    int E2 = E / 2;

    int NBG   = (N + GSIZE - 1) >> GBITS;          // 782
    int nblkH = (E2 + PPC - 1) / PPC;              // 391
    int MH    = NBG * nblkH;                       // ~306K
    int nchA  = (MH + CBLK - 1) / CBLK;            // ~598

    // Workspace (8B aligned first):
    // binned[E] u64 | ab[N] float2 | dsi[N] | diag2[N] | y_h[N*D] u16 |
    // bhist[MH] | bsum[nchA] | rbase_g[N] | rcnt_g[N]
    char* wp = (char*)d_ws;
    ull*    binned = (ull*)wp;    wp += (size_t)E * 8;
    float2* ab     = (float2*)wp; wp += (size_t)N * 8;
    float*  dsi    = (float*)wp;  wp += (size_t)N * 4;
    float*  diag2  = (float*)wp;  wp += (size_t)N * 4;
    unsigned short* y_h = (unsigned short*)wp; wp += (size_t)N * D * 2;
    int*    bhist  = (int*)wp;    wp += (size_t)MH * 4;
    int*    bsum   = (int*)wp;    wp += (size_t)nchA * 4;
    int*    rbase_g= (int*)wp;    wp += (size_t)N * 4;
    int*    rcnt_g = (int*)wp;    wp += (size_t)N * 4;

    float* out = (float*)d_out;

    int nbN = (N + BLKP - 1) / BLKP;               // 196

    k_pre_hist<<<nbN + nblkH, BLKP, 0, stream>>>(x, sheafW, linW, linb, ei, ab, y_h,
                                                 bhist, N, E2, E, nbN, nblkH, NBG);

    void* args[] = { (void*)&ei, (void*)&ab, (void*)&bhist, (void*)&bsum,
                     (void*)&binned, (void*)&y_h, (void*)&x, (void*)&dsi,
                     (void*)&diag2, (void*)&rbase_g, (void*)&rcnt_g, (void*)&out,
                     (void*)&E2, (void*)&E, (void*)&nblkH, (void*)&NBG,
                     (void*)&N, (void*)&MH, (void*)&nchA };
    hipLaunchCooperativeKernel((const void*)k_coop, dim3(GRID), dim3(CBLK),
                               args, 0, stream);
}

// Round 14
// 92.110 us; speedup vs baseline: 3.4945x; 3.4945x over previous
//
#include <hip/hip_runtime.h>

#define D 32
#define GBITS 6
#define GSIZE 64               // rows per group
#define BLK 256
#define PPC 4096               // pairs per hist/scatter chunk
#define IPT 16                 // PPC / BLK
#define CAP 2560               // LDS item capacity per group (mean 2048, ~11 sigma)

typedef unsigned long long ull;
typedef unsigned int uint;

static __device__ __forceinline__ unsigned short f2h(float f) {
    _Float16 h = (_Float16)f;
    return __builtin_bit_cast(unsigned short, h);
}
static __device__ __forceinline__ float h2f(unsigned short u) {
    return (float)__builtin_bit_cast(_Float16, u);
}
static __device__ __forceinline__ float ftanh(float u) {
    u = fminf(fmaxf(u, -15.f), 15.f);
    float e = __expf(2.f * u);
    return (e - 1.f) / (e + 1.f);
}

// ---------------------------------------------------------------------------
// K1 (fused): blocks [0,nbN) per-node precompute (ab + f16 y_h);
//             blocks [nbN,...) blocked bin histogram (bin = row >> GBITS).
// ---------------------------------------------------------------------------
__global__ void k_pre_hist(const float* __restrict__ x,
                           const float* __restrict__ sheafW,
                           const float* __restrict__ linW,
                           const float* __restrict__ linb,
                           const int* __restrict__ ei,
                           float2* __restrict__ ab,
                           unsigned short* __restrict__ y_h,
                           int* __restrict__ bhist,
                           int N, int E2, int E, int nbN, int nblkH, int NBG) {
    if (blockIdx.x < nbN) {
        __shared__ float sW[D * D];
        __shared__ float sB[D];
        __shared__ float sS[2 * D];
        for (int i = threadIdx.x; i < D * D; i += blockDim.x) sW[i] = linW[i];
        if (threadIdx.x < D) sB[threadIdx.x] = linb[threadIdx.x];
        if (threadIdx.x < 2 * D) sS[threadIdx.x] = sheafW[threadIdx.x];
        __syncthreads();

        uint n = blockIdx.x * blockDim.x + threadIdx.x;
        if (n >= (uint)N) return;

        float xv[D];
        const float4* xp = reinterpret_cast<const float4*>(x + n * (uint)D);
#pragma unroll
        for (int i = 0; i < D / 4; ++i) {
            float4 v = xp[i];
            xv[4 * i + 0] = v.x; xv[4 * i + 1] = v.y;
            xv[4 * i + 2] = v.z; xv[4 * i + 3] = v.w;
        }

        float av = 0.f, bv = 0.f;
#pragma unroll
        for (int d = 0; d < D; ++d) { av += xv[d] * sS[d]; bv += xv[d] * sS[D + d]; }
        ab[n] = make_float2(av, bv);

        unsigned short yh[D];
#pragma unroll
        for (int j = 0; j < D; ++j) {
            float s = sB[j];
#pragma unroll
            for (int d = 0; d < D; ++d) s += xv[d] * sW[j * D + d];
            yh[j] = f2h(s);
        }
        uint4* dst = reinterpret_cast<uint4*>(y_h + n * (uint)D);
        const uint4* src = reinterpret_cast<const uint4*>(yh);
#pragma unroll
        for (int q = 0; q < D / 8; ++q) dst[q] = src[q];
    } else {
        __shared__ int hist[1024];
        int blk = blockIdx.x - nbN;
        for (int i = threadIdx.x; i < NBG; i += BLK) hist[i] = 0;
        __syncthreads();
        int base = blk * PPC;
#pragma unroll
        for (int k = 0; k < IPT; ++k) {
            int i = base + k * BLK + threadIdx.x;
            if (i < E2) {
                int s = ei[i];
                int t = ei[E + i];
                atomicAdd(&hist[s >> GBITS], 1);
                atomicAdd(&hist[t >> GBITS], 1);
            }
        }
        __syncthreads();
        for (int i = threadIdx.x; i < NBG; i += BLK)
            bhist[(size_t)i * nblkH + blk] = hist[i];
    }
}

// ---------------------------------------------------------------------------
// Scan level A: 256-elem blocks, local exclusive in place + block sums.
// ---------------------------------------------------------------------------
__global__ void k_scanA(int* __restrict__ data, int* __restrict__ bsum, int M) {
    __shared__ int s[256];
    int t = threadIdx.x;
    int i = blockIdx.x * 256 + t;
    int v = (i < M) ? data[i] : 0;
    s[t] = v;
    __syncthreads();
#pragma unroll
    for (int o = 1; o < 256; o <<= 1) {
        int tmp = (t >= o) ? s[t - o] : 0;
        __syncthreads();
        s[t] += tmp;
        __syncthreads();
    }
    if (i < M) data[i] = s[t] - v;
    if (t == 255) bsum[blockIdx.x] = s[255];
}

// ---------------------------------------------------------------------------
// Scan level B: one 1024-thread block, in-place exclusive scan of NB elems.
// ---------------------------------------------------------------------------
__global__ void k_scanB(int* __restrict__ data, int NB) {
    __shared__ int s[1024];
    int t = threadIdx.x;
    int per = (NB + 1023) >> 10;
    int beg = t * per;
    int end_ = min(beg + per, NB);
    int sum = 0;
    for (int i = beg; i < end_; ++i) sum += data[i];
    s[t] = sum;
    __syncthreads();
#pragma unroll
    for (int o = 1; o < 1024; o <<= 1) {
        int tmp = (t >= o) ? s[t - o] : 0;
        __syncthreads();
        s[t] += tmp;
        __syncthreads();
    }
    int run = s[t] - sum;
    for (int i = beg; i < end_; ++i) { int v = data[i]; data[i] = run; run += v; }
}

// ---------------------------------------------------------------------------
// K4: scatter — recomputes maps from ab, packs (row<<48|col<<32|m16|mr16),
//     writes directly into bin-grouped order via LDS cursors.
//     All hot indices 32-bit unsigned.
// ---------------------------------------------------------------------------
__global__ void k_scatter(const int* __restrict__ ei,
                          const float2* __restrict__ ab,
                          const int* __restrict__ bhist,
                          const int* __restrict__ bsum,
                          ull* __restrict__ binned,
                          int E2, int E, int nblkH, int NBG) {
    __shared__ int cursor[1024];
    for (int i = threadIdx.x; i < NBG; i += BLK) {
        int idx = i * nblkH + blockIdx.x;
        cursor[i] = bhist[idx] + bsum[idx >> 8];
    }
    __syncthreads();
    int base = blockIdx.x * PPC;
#pragma unroll
    for (int k = 0; k < IPT; ++k) {
        int i = base + k * BLK + threadIdx.x;
        if (i < E2) {
            uint s = (uint)ei[i];
            uint t = (uint)ei[E + i];
            float2 as = ab[s], at = ab[t];
            float m  = ftanh(as.x + at.y);
            float mr = ftanh(at.x + as.y);
            ull hm = f2h(m), hmr = f2h(mr);
            uint pos = (uint)atomicAdd(&cursor[s >> GBITS], 1);
            binned[pos] = ((ull)s << 48) | ((ull)t << 32) | (hm << 16) | hmr;
            uint pos2 = (uint)atomicAdd(&cursor[t >> GBITS], 1);
            binned[pos2] = ((ull)t << 48) | ((ull)s << 32) | (hmr << 16) | hm;
        }
    }
}

// ---------------------------------------------------------------------------
// K5: per-group diag + row histogram (scalar LDS atomics, 2/item)
//     -> dsi, diag2 (=dm*ds^2), rbase (group-relative), rcnt.
// ---------------------------------------------------------------------------
__global__ void k_diag(const ull* __restrict__ binned,
                       const int* __restrict__ bhist,
                       const int* __restrict__ bsum,
                       float* __restrict__ dsi, float* __restrict__ diag2,
                       int* __restrict__ rbase_g, int* __restrict__ rcnt_g,
                       int E, int nblkH, int NBG, int N) {
    __shared__ float rdiag[GSIZE];
    __shared__ int rhist[GSIZE];
    __shared__ int ss[GSIZE];
    __shared__ int sgs[2];
    int g = blockIdx.x, t = threadIdx.x;
    if (t < GSIZE) { rdiag[t] = 0.f; rhist[t] = 0; }
    if (t < 2) {
        int gg = g + t;
        if (gg < NBG) {
            int idx = gg * nblkH;
            sgs[t] = bhist[idx] + bsum[idx >> 8];
        } else sgs[t] = E;
    }
    __syncthreads();
    int gstart = sgs[0], gend = sgs[1];
    for (int k = gstart + t; k < gend; k += BLK) {
        ull it = binned[k];
        int r = (int)(it >> 48) & (GSIZE - 1);
        float m = h2f((unsigned short)((it >> 16) & 0xFFFF));
        atomicAdd(&rdiag[r], m * m);
        atomicAdd(&rhist[r], 1);
    }
    __syncthreads();
    // exclusive scan of rhist (64 entries; all 256 threads hit barriers)
    int v = (t < GSIZE) ? rhist[t] : 0;
    if (t < GSIZE) ss[t] = v;
    __syncthreads();
#pragma unroll
    for (int o = 1; o < GSIZE; o <<= 1) {
        int tmp = 0;
        if (t < GSIZE && t >= o) tmp = ss[t - o];
        __syncthreads();
        if (t < GSIZE) ss[t] += tmp;
        __syncthreads();
    }
    int n0 = g << GBITS;
    if (t < GSIZE) {
        int n = n0 + t;
        if (n < N) {
            float dm = rdiag[t];
            float ds = rsqrtf(dm + 1.0f);
            dsi[n] = ds;
            diag2[n] = dm * ds * ds;     // full diagonal coefficient
            rbase_g[n] = ss[t] - v;      // group-relative exclusive offset
            rcnt_g[n] = v;
        }
    }
}

// ---------------------------------------------------------------------------
// K6: fused sort+gather per group.  rbase/rcnt precomputed by k_diag, so only
//     ONE binned pass: fold dsi[col], counting-scatter to row-sorted LDS
//     (packed u32: col16 | f16(m*mr*dsi[col])), then 16 half-waves walk rows.
//     All per-item indices 32-bit (buffers < 4 MB; col*D+lane < 2^24).
//     out = x - diag2[n]*y[n,:] + dsi[n] * sum w * y[col,:]
// ---------------------------------------------------------------------------
__global__ __launch_bounds__(512) void k_gather_fused(
        const ull* __restrict__ binned,
        const int* __restrict__ bhist,
        const int* __restrict__ bsum,
        const unsigned short* __restrict__ y_h,
        const float* __restrict__ x,
        const float* __restrict__ dsi,
        const float* __restrict__ diag2,
        const int* __restrict__ rbase_g,
        const int* __restrict__ rcnt_g,
        float* __restrict__ out,
        int E, int nblkH, int NBG, int N) {
    __shared__ unsigned int sortedw[CAP];      // 10 KB
    __shared__ int rbase[GSIZE];
    __shared__ int rcnt[GSIZE];
    __shared__ int cur[GSIZE];
    __shared__ float sds[GSIZE];
    __shared__ float sdg[GSIZE];
    __shared__ int sgs[1];
    int g = blockIdx.x, t = threadIdx.x;
    int n0 = g << GBITS;
    if (t < GSIZE) {
        int n = n0 + t;
        if (n < N) {
            sds[t] = dsi[n]; sdg[t] = diag2[n];
            int rb = rbase_g[n];
            rbase[t] = rb; cur[t] = rb; rcnt[t] = rcnt_g[n];
        } else { rbase[t] = 0; cur[t] = 0; rcnt[t] = 0; }
    }
    if (t == 0) {
        int idx = g * nblkH;
        sgs[0] = bhist[idx] + bsum[idx >> 8];
    }
    __syncthreads();
    uint gstart = (uint)sgs[0];
    int cnt = 0;
    {
        int lastn = min(n0 + GSIZE, N) - 1;
        if (lastn >= n0) cnt = min(rbase[lastn - n0] + rcnt[lastn - n0], CAP);
    }

    // single binned pass: fold dsi[col], counting-scatter to row-sorted LDS
    for (uint k = t; k < (uint)cnt; k += 512) {
        ull it = binned[gstart + k];
        int r = (int)(it >> 48) & (GSIZE - 1);
        uint c = (uint)((it >> 32) & 0xFFFF);
        float w = h2f((unsigned short)((it >> 16) & 0xFFFF)) *
                  h2f((unsigned short)(it & 0xFFFF)) * dsi[c];
        int pos = atomicAdd(&cur[r], 1);
        sortedw[pos] = (c << 16) | (uint)f2h(w);
    }
    __syncthreads();

    // walk: 16 half-waves, each owns rows hw, hw+16, ...; lane = dim
    int hw = t >> 5;
    uint lane = (uint)(t & 31);
    int rows = min(GSIZE, N - n0);
    for (int r = hw; r < rows; r += 16) {
        int beg = rbase[r];
        int end_ = beg + rcnt[r];
        float acc = 0.f;
        int k = beg;
        for (; k + 4 <= end_; k += 4) {
            uint e0 = sortedw[k + 0];
            uint e1 = sortedw[k + 1];
            uint e2 = sortedw[k + 2];
            uint e3 = sortedw[k + 3];
            float v0 = h2f(y_h[(e0 >> 16) * (uint)D + lane]);
            float v1 = h2f(y_h[(e1 >> 16) * (uint)D + lane]);
            float v2 = h2f(y_h[(e2 >> 16) * (uint)D + lane]);
            float v3 = h2f(y_h[(e3 >> 16) * (uint)D + lane]);
            acc += h2f((unsigned short)(e0 & 0xFFFF)) * v0;
            acc += h2f((unsigned short)(e1 & 0xFFFF)) * v1;
            acc += h2f((unsigned short)(e2 & 0xFFFF)) * v2;
            acc += h2f((unsigned short)(e3 & 0xFFFF)) * v3;
        }
        for (; k < end_; ++k) {
            uint e = sortedw[k];
            acc += h2f((unsigned short)(e & 0xFFFF)) *
                   h2f(y_h[(e >> 16) * (uint)D + lane]);
        }
        uint p = (uint)(n0 + r) * (uint)D + lane;
        float yown = h2f(y_h[p]);
        out[p] = x[p] - sdg[r] * yown + sds[r] * acc;
    }
}

extern "C" void kernel_launch(void* const* d_in, const int* in_sizes, int n_in,
                              void* d_out, int out_size, void* d_ws, size_t ws_size,
                              hipStream_t stream) {
    const float* x      = (const float*)d_in[0];
    const float* sheafW = (const float*)d_in[1];
    const float* linW   = (const float*)d_in[2];
    const float* linb   = (const float*)d_in[3];
    const int*   ei     = (const int*)d_in[4];

    int N  = in_sizes[0] / D;
    int E  = in_sizes[4] / 2;
    int E2 = E / 2;

    int NBG   = (N + GSIZE - 1) >> GBITS;          // 782
    int nblkH = (E2 + PPC - 1) / PPC;              // 196
    int MH    = NBG * nblkH;                       // ~153K
    int nblkA = (MH + 255) / 256;                  // ~599

    // Workspace (8B aligned first):
    // binned[E] u64 | ab[N] float2 | dsi[N] | diag2[N] | y_h[N*D] u16 |
    // bhist[MH] | bsumA[nblkA] | rbase_g[N] | rcnt_g[N]
    char* wp = (char*)d_ws;
    ull*    binned = (ull*)wp;    wp += (size_t)E * 8;
    float2* ab     = (float2*)wp; wp += (size_t)N * 8;
    float*  dsi    = (float*)wp;  wp += (size_t)N * 4;
    float*  diag2  = (float*)wp;  wp += (size_t)N * 4;
    unsigned short* y_h = (unsigned short*)wp; wp += (size_t)N * D * 2;
    int*    bhist  = (int*)wp;    wp += (size_t)MH * 4;
    int*    bsumA  = (int*)wp;    wp += (size_t)nblkA * 4;
    int*    rbase_g= (int*)wp;    wp += (size_t)N * 4;
    int*    rcnt_g = (int*)wp;    wp += (size_t)N * 4;

    float* out = (float*)d_out;

    int nbN = (N + BLK - 1) / BLK;                 // 196

    k_pre_hist<<<nbN + nblkH, BLK, 0, stream>>>(x, sheafW, linW, linb, ei, ab, y_h,
                                                bhist, N, E2, E, nbN, nblkH, NBG);
    k_scanA<<<nblkA, 256, 0, stream>>>(bhist, bsumA, MH);
    k_scanB<<<1, 1024, 0, stream>>>(bsumA, nblkA);
    k_scatter<<<nblkH, BLK, 0, stream>>>(ei, ab, bhist, bsumA, binned, E2, E, nblkH, NBG);
    k_diag<<<NBG, BLK, 0, stream>>>(binned, bhist, bsumA, dsi, diag2, rbase_g, rcnt_g,
                                    E, nblkH, NBG, N);
    k_gather_fused<<<NBG, 512, 0, stream>>>(binned, bhist, bsumA, y_h, x, dsi, diag2,
                                            rbase_g, rcnt_g, out, E, nblkH, NBG, N);
}